// Round 1
// 16830.782 us; speedup vs baseline: 1.2782x; 1.2782x over previous
//
#include <hip/hip_runtime.h>
#include <hip/hip_bf16.h>
#include <math.h>

// Problem constants (fixed by setup_inputs)
#define TT 1024
#define CC 1024
#define HH 16
#define HD 64
#define FF 4096
#define VV 32000
#define LL 8
#define BBATCH 2
#define MM (BBATCH*TT)   // 2048 rows

typedef __attribute__((ext_vector_type(8))) short bf16x8;
typedef __attribute__((ext_vector_type(4))) float f32x4;

// ---------------- embed: x[b,t,:] = tok_emb[idx[b,t],:] + pos_emb[0,t,:] ----------------
__global__ __launch_bounds__(256) void k_embed(const int* __restrict__ idx,
        const float* __restrict__ tok, const float* __restrict__ pos,
        float* __restrict__ x) {
    int i = blockIdx.x * 256 + threadIdx.x;     // index in float4 units over M*C/4
    int c4 = i & (CC/4 - 1);                    // 0..255
    int bt = i >> 8;                            // row 0..2047
    int t  = bt & (TT - 1);
    int tk = idx[bt];
    float4 a = ((const float4*)tok)[(size_t)tk * (CC/4) + c4];
    float4 p = ((const float4*)pos)[(size_t)t  * (CC/4) + c4];
    float4 r; r.x=a.x+p.x; r.y=a.y+p.y; r.z=a.z+p.z; r.w=a.w+p.w;
    ((float4*)x)[i] = r;
}

// ---------------- LayerNorm: one block per row, C=1024, block=256 ----------------
__global__ __launch_bounds__(256) void k_lnorm(const float* __restrict__ x,
        const float* __restrict__ w, const float* __restrict__ b,
        float* __restrict__ out) {
    __shared__ float rs[4], rs2[4];
    int row = blockIdx.x, tid = threadIdx.x;
    float4 xv = ((const float4*)x)[(size_t)row * (CC/4) + tid];
    float s  = xv.x + xv.y + xv.z + xv.w;
    float s2 = xv.x*xv.x + xv.y*xv.y + xv.z*xv.z + xv.w*xv.w;
    #pragma unroll
    for (int off = 32; off > 0; off >>= 1) {
        s  += __shfl_down(s,  off, 64);
        s2 += __shfl_down(s2, off, 64);
    }
    if ((tid & 63) == 0) { rs[tid >> 6] = s; rs2[tid >> 6] = s2; }
    __syncthreads();
    float S  = rs[0] + rs[1] + rs[2] + rs[3];
    float S2 = rs2[0] + rs2[1] + rs2[2] + rs2[3];
    float mu  = S * (1.0f / CC);
    float var = S2 * (1.0f / CC) - mu * mu;
    float rstd = rsqrtf(var + 1e-5f);
    float4 wv = ((const float4*)w)[tid];
    float4 bv = ((const float4*)b)[tid];
    float4 o;
    o.x = (xv.x - mu) * rstd * wv.x + bv.x;
    o.y = (xv.y - mu) * rstd * wv.y + bv.y;
    o.z = (xv.z - mu) * rstd * wv.z + bv.z;
    o.w = (xv.w - mu) * rstd * wv.w + bv.w;
    ((float4*)out)[(size_t)row * (CC/4) + tid] = o;
}

// ---------------- split-bf16 MFMA GEMM ----------------
// out[M,N] = A[M,K] @ B[K,N] (+bias)(+gelu|+res), fp32 in/out.
// Each fp32 value is split x = hi + lo (two bf16, truncation); the product uses
// 3 MFMAs: hi*hi + hi*lo + lo*hi  (lo*lo term ~2^-32 rel, dropped).
// Tile: BM=BN=128, BK=32; 4 waves, each owns a 64x64 sub-tile = 4x4 fragments
// of v_mfma_f32_16x16x32_bf16. LDS tiles stored K-contiguous [row][k] with a
// chunk-XOR swizzle (chunk ^= (row>>1)&3) to balance LDS bank quads for both
// the staging writes and the ds_read_b128 fragment reads.
#define BM 128
#define BN 128
#define BK 32

struct GemmOut { const float* B; const float* bias; float* out; };

__device__ __forceinline__ int lds_off(int row, int chunk) {
    // offset in bf16 elements; row stride 32, 4 chunks of 8 bf16 (16B) each
    return (row << 5) + ((chunk ^ ((row >> 1) & 3)) << 3);
}

__device__ __forceinline__ void bsplit(float x, unsigned short& h, unsigned short& lo) {
    unsigned int b = __float_as_uint(x);
    h = (unsigned short)(b >> 16);
    float fh = __uint_as_float(b & 0xffff0000u);
    lo = (unsigned short)(__float_as_uint(x - fh) >> 16);
}

__device__ __forceinline__ uint4 pack8(const unsigned short* s) {
    return make_uint4((unsigned)s[0] | ((unsigned)s[1] << 16),
                      (unsigned)s[2] | ((unsigned)s[3] << 16),
                      (unsigned)s[4] | ((unsigned)s[5] << 16),
                      (unsigned)s[6] | ((unsigned)s[7] << 16));
}

__device__ __forceinline__ float gelu_exact(float v) {
    return 0.5f * v * (1.0f + erff(v * 0.70710678118654752f));
}

__global__ __launch_bounds__(256, 2) void k_mgemm(const float* __restrict__ A,
        GemmOut g0, GemmOut g1, GemmOut g2,
        const float* __restrict__ res, int M, int N, int K, int mode) {
    __shared__ unsigned short Ah[BM*BK], Al[BM*BK], Bh[BM*BK], Bl[BM*BK];
    const GemmOut g = (blockIdx.z == 0) ? g0 : ((blockIdx.z == 1) ? g1 : g2);
    const float* __restrict__ Bw = g.B;
    const int tid = threadIdx.x;
    const int w  = tid >> 6, l = tid & 63;
    const int wm = w >> 1, wn = w & 1;          // 2x2 waves, 64x64 each
    const int fl = l & 15, fg = l >> 4;         // fragment lane decomposition
    const int bm = blockIdx.y * BM, bn = blockIdx.x * BN;

    // A staging: thread loads 4x float4; row = w*8 + (l>>3) + it*32, k = kq*4..+3
    const int a_row = w * 8 + (l >> 3);
    const int a_kq  = l & 7;
    // B staging: thread owns n = {2p, 2p+1}, k = oct*8..+7 (transposed into LDS)
    const int b_oct = l & 3;
    const int b_p   = (l >> 2) + w * 16;        // 0..63

    f32x4 acc[4][4] = {};
    const float* Aptr = A  + (size_t)(bm + a_row) * K + a_kq * 4;
    const float* Bptr = Bw + (size_t)b_oct * 8 * N + bn + 2 * b_p;

    for (int k0 = 0; k0 < K; k0 += BK) {
        // ---- global loads (no LDS dep: overlap with prev iter's MFMA reads) ----
        float4 av[4];
        #pragma unroll
        for (int it = 0; it < 4; ++it)
            av[it] = *(const float4*)(Aptr + (size_t)(it * 32) * K + k0);
        float2 bv[8];
        #pragma unroll
        for (int j = 0; j < 8; ++j)
            bv[j] = *(const float2*)(Bptr + (size_t)(k0 + j) * N);

        __syncthreads();   // prev iteration's fragment reads done

        // ---- convert + stage A ----
        #pragma unroll
        for (int it = 0; it < 4; ++it) {
            unsigned short hh[4], ll[4];
            bsplit(av[it].x, hh[0], ll[0]);
            bsplit(av[it].y, hh[1], ll[1]);
            bsplit(av[it].z, hh[2], ll[2]);
            bsplit(av[it].w, hh[3], ll[3]);
            int off = lds_off(a_row + it * 32, a_kq >> 1) + (a_kq & 1) * 4;
            *(ushort4*)&Ah[off] = make_ushort4(hh[0], hh[1], hh[2], hh[3]);
            *(ushort4*)&Al[off] = make_ushort4(ll[0], ll[1], ll[2], ll[3]);
        }
        // ---- convert + stage B (register transpose: [k][n] -> [n][k]) ----
        {
            unsigned short bh0[8], bl0[8], bh1[8], bl1[8];
            #pragma unroll
            for (int j = 0; j < 8; ++j) {
                bsplit(bv[j].x, bh0[j], bl0[j]);
                bsplit(bv[j].y, bh1[j], bl1[j]);
            }
            const int o1 = lds_off(2 * b_p,     b_oct);
            const int o2 = lds_off(2 * b_p + 1, b_oct);
            *(uint4*)&Bh[o1] = pack8(bh0);
            *(uint4*)&Bl[o1] = pack8(bl0);
            *(uint4*)&Bh[o2] = pack8(bh1);
            *(uint4*)&Bl[o2] = pack8(bl1);
        }
        __syncthreads();   // tiles visible

        // ---- fragment loads (ds_read_b128) + 48 MFMA ----
        bf16x8 a_h[4], a_l[4], f_h[4], f_l[4];
        #pragma unroll
        for (int mi = 0; mi < 4; ++mi) {
            int off = lds_off(wm * 64 + mi * 16 + fl, fg);
            a_h[mi] = *(const bf16x8*)&Ah[off];
            a_l[mi] = *(const bf16x8*)&Al[off];
        }
        #pragma unroll
        for (int ni = 0; ni < 4; ++ni) {
            int off = lds_off(wn * 64 + ni * 16 + fl, fg);
            f_h[ni] = *(const bf16x8*)&Bh[off];
            f_l[ni] = *(const bf16x8*)&Bl[off];
        }
        #pragma unroll
        for (int mi = 0; mi < 4; ++mi) {
            #pragma unroll
            for (int ni = 0; ni < 4; ++ni) {
                acc[mi][ni] = __builtin_amdgcn_mfma_f32_16x16x32_bf16(a_h[mi], f_h[ni], acc[mi][ni], 0, 0, 0);
                acc[mi][ni] = __builtin_amdgcn_mfma_f32_16x16x32_bf16(a_h[mi], f_l[ni], acc[mi][ni], 0, 0, 0);
                acc[mi][ni] = __builtin_amdgcn_mfma_f32_16x16x32_bf16(a_l[mi], f_h[ni], acc[mi][ni], 0, 0, 0);
            }
        }
    }

    // ---- epilogue: C/D layout row = fg*4 + r, col = fl ----
    float* outp = g.out;
    const float* bias = g.bias;
    #pragma unroll
    for (int ni = 0; ni < 4; ++ni) {
        const int col = bn + wn * 64 + ni * 16 + fl;
        const float bias_v = bias ? bias[col] : 0.0f;
        #pragma unroll
        for (int mi = 0; mi < 4; ++mi) {
            #pragma unroll
            for (int r = 0; r < 4; ++r) {
                const int row = bm + wm * 64 + mi * 16 + fg * 4 + r;
                const size_t o = (size_t)row * N + col;
                float v = acc[mi][ni][r] + bias_v;
                if (mode == 1)      v = gelu_exact(v);
                else if (mode == 2) v += res[o];
                outp[o] = v;
            }
        }
    }
}

// ---------------- causal attention, one block per (b,h,t); adds result into x ----------------
// q,k,v stored as [B,T,H,hd] (i.e. [M, C] from projection); block=256
__global__ __launch_bounds__(256) void k_attn(const float* __restrict__ q,
        const float* __restrict__ kk, const float* __restrict__ vv,
        float* __restrict__ x) {
    const int t = blockIdx.x, h = blockIdx.y, b = blockIdx.z;
    const int tid = threadIdx.x;
    __shared__ float sc[TT];
    __shared__ float qs[HD];
    __shared__ float red[4];
    __shared__ float ys[4][HD];
    const size_t rowoff = ((size_t)(b*TT + t)) * CC + h*HD;
    if (tid < 16) ((float4*)qs)[tid] = *(const float4*)(q + rowoff + tid*4);
    __syncthreads();
    const int nk = t + 1;
    const float scale = 0.125f;  // 1/sqrt(64)
    for (int s = tid; s < nk; s += 256) {
        const float* kr = kk + ((size_t)(b*TT + s)) * CC + h*HD;
        float acc = 0.f;
        #pragma unroll
        for (int d = 0; d < HD; d += 4) {
            float4 kv = *(const float4*)(kr + d);
            acc += qs[d]*kv.x + qs[d+1]*kv.y + qs[d+2]*kv.z + qs[d+3]*kv.w;
        }
        sc[s] = acc * scale;
    }
    __syncthreads();
    // max
    float m = -3.4e38f;
    for (int s = tid; s < nk; s += 256) m = fmaxf(m, sc[s]);
    #pragma unroll
    for (int off = 32; off > 0; off >>= 1) m = fmaxf(m, __shfl_down(m, off, 64));
    if ((tid & 63) == 0) red[tid >> 6] = m;
    __syncthreads();
    m = fmaxf(fmaxf(red[0], red[1]), fmaxf(red[2], red[3]));
    __syncthreads();  // red about to be reused
    // exp + sum (each thread rewrites only its own sc[s])
    float sum = 0.f;
    for (int s = tid; s < nk; s += 256) {
        float e = expf(sc[s] - m);
        sc[s] = e;
        sum += e;
    }
    #pragma unroll
    for (int off = 32; off > 0; off >>= 1) sum += __shfl_down(sum, off, 64);
    if ((tid & 63) == 0) red[tid >> 6] = sum;
    __syncthreads();  // also guarantees all sc[] exp writes visible
    sum = red[0] + red[1] + red[2] + red[3];
    float inv = 1.0f / sum;
    // y[d] = sum_s p[s] * v[s,d]; threads = 4 chunks x 64 dims (coalesced v reads)
    const int d = tid & 63, ch = tid >> 6;
    float yd = 0.f;
    for (int s = ch; s < nk; s += 4)
        yd += sc[s] * vv[((size_t)(b*TT + s)) * CC + h*HD + d];
    ys[ch][d] = yd;
    __syncthreads();
    if (tid < 64) {
        float r = (ys[0][tid] + ys[1][tid] + ys[2][tid] + ys[3][tid]) * inv;
        x[rowoff + tid] += r;
    }
}

extern "C" void kernel_launch(void* const* d_in, const int* in_sizes, int n_in,
                              void* d_out, int out_size, void* d_ws, size_t ws_size,
                              hipStream_t stream) {
    const int*   idx   = (const int*)  d_in[0];
    const float* tok   = (const float*)d_in[1];
    const float* pos   = (const float*)d_in[2];
    const float* ln1w  = (const float*)d_in[3];
    const float* ln1b  = (const float*)d_in[4];
    const float* wq    = (const float*)d_in[5];
    const float* bq    = (const float*)d_in[6];
    const float* wk    = (const float*)d_in[7];
    const float* bk    = (const float*)d_in[8];
    const float* wv    = (const float*)d_in[9];
    const float* bv    = (const float*)d_in[10];
    const float* ln2w  = (const float*)d_in[11];
    const float* ln2b  = (const float*)d_in[12];
    const float* w1    = (const float*)d_in[13];
    const float* b1    = (const float*)d_in[14];
    const float* w2    = (const float*)d_in[15];
    const float* b2    = (const float*)d_in[16];
    const float* lnfw  = (const float*)d_in[17];
    const float* lnfb  = (const float*)d_in[18];
    const float* headw = (const float*)d_in[19];
    float* out = (float*)d_out;

    // workspace layout (floats): x[2Mi] | h[2Mi] | overlay{ q,k,v (3x2Mi) | ffn (8Mi) }
    float* ws = (float*)d_ws;
    const size_t MC = (size_t)MM * CC;   // 2 Mi floats
    float* x    = ws;
    float* hbuf = ws + MC;
    float* qb   = ws + 2*MC;
    float* kb   = qb + MC;
    float* vb   = kb + MC;
    float* ffn  = qb;                    // reused after attention, needs MM*FF floats

    k_embed<<<(MM*CC/4)/256, 256, 0, stream>>>(idx, tok, pos, x);

    dim3 gProj(CC/BN, MM/BM, 3);    // 8 x 16 x 3 (fused QKV)
    dim3 gFfn1(FF/BN, MM/BM, 1);    // 32 x 16
    dim3 gFfn2(CC/BN, MM/BM, 1);    // 8 x 16
    dim3 gHead(VV/BN, MM/BM, 1);    // 250 x 16
    dim3 gAttn(TT, HH, BBATCH);

    for (int l = 0; l < LL; ++l) {
        k_lnorm<<<MM, 256, 0, stream>>>(x, ln1w + l*CC, ln1b + l*CC, hbuf);
        GemmOut gq = { wq + (size_t)l*CC*CC, bq + l*CC, qb };
        GemmOut gk = { wk + (size_t)l*CC*CC, bk + l*CC, kb };
        GemmOut gv = { wv + (size_t)l*CC*CC, bv + l*CC, vb };
        k_mgemm<<<gProj, 256, 0, stream>>>(hbuf, gq, gk, gv, nullptr, MM, CC, CC, 0);
        k_attn<<<gAttn, 256, 0, stream>>>(qb, kb, vb, x);
        k_lnorm<<<MM, 256, 0, stream>>>(x, ln2w + l*CC, ln2b + l*CC, hbuf);
        GemmOut gf1 = { w1 + (size_t)l*CC*FF, b1 + l*FF, ffn };
        k_mgemm<<<gFfn1, 256, 0, stream>>>(hbuf, gf1, gf1, gf1, nullptr, MM, FF, CC, 1);
        GemmOut gf2 = { w2 + (size_t)l*FF*CC, b2 + l*CC, x };
        k_mgemm<<<gFfn2, 256, 0, stream>>>(ffn, gf2, gf2, gf2, x, MM, CC, FF, 2);
    }
    k_lnorm<<<MM, 256, 0, stream>>>(x, lnfw, lnfb, hbuf);
    GemmOut gh = { headw, nullptr, out };
    k_mgemm<<<gHead, 256, 0, stream>>>(hbuf, gh, gh, gh, nullptr, MM, VV, CC, 0);
}